// Round 8
// baseline (951.132 us; speedup 1.0000x reference)
//
#include <hip/hip_runtime.h>
#include <hip/hip_bf16.h>
#include <climits>

#define B_ 2
#define V_ 4
#define H_ 120
#define W_ 160
#define C_ 96
#define NVOX 200000
#define GRID_ 128
#define NSTEPS 156
#define NRAYS (B_*V_*H_*W_)       // 153600
#define CHUNK 32                  // sorted-list entries per wave in chunk phase
#define NB 1024                   // persistent blocks: 4/CU guaranteed co-resident
#define BT 256
#define NT (NB*BT)                // 262144 threads
#define NWAVE (NB*4)              // 4096 waves
#define NWT (NRAYS/16)            // 9600 march wave-tasks (16 rays each)
#define NVB ((NVOX+255)/256)      // 782 alloc vblocks

// Monotonic grid barrier: every block arrives (release), spins until all NB
// blocks of this phase arrived (acquire). ctr zeroed by host-side memset each
// launch; 6 phases -> final value 6*NB. Safe because all NB blocks are
// co-resident (__launch_bounds__(256,4) => >=4 blocks/CU * 256 CU = 1024).
__device__ __forceinline__ void gbar(int* ctr, int target) {
    __syncthreads();
    if (threadIdx.x == 0) {
        __threadfence();
        __hip_atomic_fetch_add(ctr, 1, __ATOMIC_ACQ_REL, __HIP_MEMORY_SCOPE_AGENT);
        while (__hip_atomic_load(ctr, __ATOMIC_ACQUIRE, __HIP_MEMORY_SCOPE_AGENT) < target)
            __builtin_amdgcn_s_sleep(2);
    }
    __syncthreads();
}

__global__ __launch_bounds__(BT, 4) void mega_kernel(
    const float* __restrict__ feats, const int* __restrict__ coords,
    const float* __restrict__ vm, const float* __restrict__ intr,
    int* __restrict__ sneg,              // 6 ints, zeroed: stores max(127-coord)=127-min
    int* __restrict__ cnt,               // NVOX, zeroed
    unsigned long long* __restrict__ mask, // 512 KB, zeroed
    int* __restrict__ gtotal,            // 1 int, zeroed
    int* __restrict__ ctr,               // 1 int, zeroed (barrier)
    int* __restrict__ tgt, int* __restrict__ segstart, int* __restrict__ cursor,
    int2* __restrict__ sorted_rt, int* __restrict__ occ,
    float* __restrict__ out, float* __restrict__ cnt_out)
{
    const int tid  = threadIdx.x;
    const int gtid = blockIdx.x * BT + tid;
    const int lane = tid & 63;
    const int wid  = tid >> 6;
    const int wvg  = blockIdx.x * 4 + wid;     // global wave id
    __shared__ int smax[B_ * 3];
    __shared__ int wtot[4];

    // ============ phase 0: per-batch 127-min via atomicMax(127-coord) =======
    if (tid < B_ * 3) smax[tid] = 0;
    __syncthreads();
    for (int i = gtid; i < NVOX; i += NT) {
        int b = coords[i * 4 + 0];
        atomicMax(&smax[b * 3 + 0], 127 - coords[i * 4 + 1]);
        atomicMax(&smax[b * 3 + 1], 127 - coords[i * 4 + 2]);
        atomicMax(&smax[b * 3 + 2], 127 - coords[i * 4 + 3]);
    }
    __syncthreads();
    if (tid < B_ * 3 && smax[tid] > 0) atomicMax(&sneg[tid], smax[tid]);
    gbar(ctr, 1 * NB);

    // ============ phase 1: occ id grid (last-dup wins) + bitmask ============
    int sh[B_ * 3];
#pragma unroll
    for (int k = 0; k < B_ * 3; ++k) sh[k] = 127 - sneg[k];   // = per-batch min
    for (int i = gtid; i < NVOX; i += NT) {
        int b = coords[i * 4 + 0];
        int x = coords[i * 4 + 1] - sh[b * 3 + 0];
        int y = coords[i * 4 + 2] - sh[b * 3 + 1];
        int z = coords[i * 4 + 3] - sh[b * 3 + 2];
        int idx = ((b * GRID_ + z) * GRID_ + y) * GRID_ + x;
        atomicMax(&occ[idx], i);          // occ uninit: reads gated by mask
        atomicOr(&mask[idx >> 6], 1ull << (idx & 63));
    }
    gbar(ctr, 2 * NB);

    // ============ phase 2: march (wave = 16 pixels x 4 step-blocks) =========
    {
        const float fx = intr[0], fy = intr[1], cx = intr[2], cy = intr[3];
        const int p = lane & 15, sub = lane >> 4;
        const int MISS = 0x7FFFFFFF;
        for (int wt = wvg; wt < NWT; wt += NWAVE) {
            int r = wt * 16 + p;
            int w = r % W_;
            int h = (r / W_) % H_;
            int v = (r / (W_ * H_)) % V_;
            int b = r / (W_ * H_ * V_);
            const float* M = vm + (size_t)(b * V_ + v) * 16;
            float dx = ((float)w + 0.5f - cx) / fx;
            float dy = ((float)h + 0.5f - cy) / fy;
            float R00 = M[0], R01 = M[1], R02 = M[2];
            float R10 = M[4], R11 = M[5], R12 = M[6];
            float R20 = M[8], R21 = M[9], R22 = M[10];
            float t0 = M[3]  - (float)sh[b * 3 + 0];
            float t1 = M[7]  - (float)sh[b * 3 + 1];
            float t2 = M[11] - (float)sh[b * 3 + 2];
            int beststep = MISS;
            for (int w0 = 0; w0 < NSTEPS; w0 += 32) {
                int lin[8]; bool ok[8];
#pragma unroll
                for (int j = 0; j < 8; ++j) {
                    int st = w0 + sub * 8 + j;
                    float t = 2.0f + 0.5f * (float)st;
                    float px = dx * t, py = dy * t, pz = t;
                    float pwx = R00 * px + R01 * py + R02 * pz + t0;
                    float pwy = R10 * px + R11 * py + R12 * pz + t1;
                    float pwz = R20 * px + R21 * py + R22 * pz + t2;
                    int ix = (int)floorf(pwx);
                    int iy = (int)floorf(pwy);
                    int iz = (int)floorf(pwz);
                    ok[j] = ((unsigned)ix < (unsigned)GRID_) &
                            ((unsigned)iy < (unsigned)GRID_) &
                            ((unsigned)iz < (unsigned)GRID_) & (st < NSTEPS);
                    int cix = min(max(ix, 0), GRID_ - 1);
                    int ciy = min(max(iy, 0), GRID_ - 1);
                    int ciz = min(max(iz, 0), GRID_ - 1);
                    lin[j] = ((b * GRID_ + ciz) * GRID_ + ciy) * GRID_ + cix;
                }
                unsigned long long u[8];
                bool same[8];
                same[0] = false;
#pragma unroll
                for (int j = 1; j < 8; ++j) same[j] = ((lin[j] >> 6) == (lin[j - 1] >> 6));
#pragma unroll
                for (int j = 0; j < 8; ++j)
                    if (!same[j]) u[j] = mask[lin[j] >> 6];
#pragma unroll
                for (int j = 1; j < 8; ++j)
                    if (same[j]) u[j] = u[j - 1];
                int local = MISS;
#pragma unroll
                for (int j = 0; j < 8; ++j) {
                    int st = w0 + sub * 8 + j;
                    if (ok[j] && ((u[j] >> (lin[j] & 63)) & 1ull)) local = min(local, st);
                }
                local = min(local, __shfl_xor(local, 16));
                local = min(local, __shfl_xor(local, 32));
                if (local != MISS) { beststep = local; break; }
            }
            if (sub == 0) {
                int res = -1;
                if (beststep != MISS) {
                    float t = 2.0f + 0.5f * (float)beststep;
                    float px = dx * t, py = dy * t, pz = t;
                    float pwx = R00 * px + R01 * py + R02 * pz + t0;
                    float pwy = R10 * px + R11 * py + R12 * pz + t1;
                    float pwz = R20 * px + R21 * py + R22 * pz + t2;
                    int ix = (int)floorf(pwx);
                    int iy = (int)floorf(pwy);
                    int iz = (int)floorf(pwz);
                    res = occ[((b * GRID_ + iz) * GRID_ + iy) * GRID_ + ix];
                }
                tgt[r] = res;
                if (res >= 0) atomicAdd(&cnt[res], 1);
            }
        }
    }
    gbar(ctr, 3 * NB);

    // ============ phase 3: segment allocator (block scan + 1 atomic) ========
    for (int vb = blockIdx.x; vb < NVB; vb += NB) {
        int i = vb * 256 + tid;
        int c = (i < NVOX) ? cnt[i] : 0;
        int x = c;
#pragma unroll
        for (int d = 1; d < 64; d <<= 1) {
            int y = __shfl_up(x, d);
            if (lane >= d) x += y;
        }
        if (lane == 63) wtot[wid] = x;
        __syncthreads();
        if (tid == 0) {
            int s0 = wtot[0], s1 = wtot[1], s2 = wtot[2], s3 = wtot[3];
            int base = atomicAdd(gtotal, s0 + s1 + s2 + s3);
            wtot[0] = base;
            wtot[1] = base + s0;
            wtot[2] = base + s0 + s1;
            wtot[3] = base + s0 + s1 + s2;
        }
        __syncthreads();
        if (i < NVOX) {
            int s = wtot[wid] + (x - c);          // exclusive position
            segstart[i] = s;
            cursor[i]   = s;
            if (c > 0) {
                int e = s + c;
                if ((s / CHUNK) != ((e - 1) / CHUNK)) {   // crossing: pre-zero row
                    float4* o = (float4*)(out + (size_t)i * C_);
#pragma unroll
                    for (int q = 0; q < C_ / 4; ++q) o[q] = make_float4(0.f, 0.f, 0.f, 0.f);
                }
            }
        }
        __syncthreads();
    }
    gbar(ctr, 4 * NB);

    // ============ phase 4: bucket rays (counting sort) ======================
    for (int r = gtid; r < NRAYS; r += NT) {
        int t = tgt[r];
        if (t >= 0) {
            int pos = atomicAdd(&cursor[t], 1);
            sorted_rt[pos] = make_int2(r, t);
        }
    }
    gbar(ctr, 5 * NB);

    // ============ phase 5: chunked segmented reduce =========================
    {
        int total = gtotal[0];
        int nch = (total + CHUNK - 1) / CHUNK;
        for (int ch = wvg; ch < nch; ch += NWAVE) {
            int a = ch * CHUNK;
            int n = min(CHUNK, total - a);
            int myr = 0, myt = 0;
            if (lane < n) { int2 e = sorted_rt[a + lane]; myr = e.x; myt = e.y; }
            float ax = 0.0f, ay = 0.0f;
            int cur = -1, run_start = 0;
            for (int k0 = 0; k0 < n; k0 += 4) {
                float2 vbuf[4]; int tt[4];
#pragma unroll
                for (int j = 0; j < 4; ++j) {
                    int k = k0 + j;
                    int rr = __shfl(myr, k);
                    tt[j]  = __shfl(myt, k);
                    vbuf[j] = make_float2(0.0f, 0.0f);
                    if (k < n && lane < 48)
                        vbuf[j] = ((const float2*)(feats + (size_t)rr * C_))[lane];
                }
#pragma unroll
                for (int j = 0; j < 4; ++j) {
                    int k = k0 + j;
                    if (k >= n) break;
                    if (tt[j] != cur) {
                        if (cur >= 0) {
                            // flush run [run_start, k)
                            int t = cur, ks = run_start;
                            int c; bool complete;
                            if (ks > 0) { c = k - ks; complete = true; }   // middle run
                            else {
                                c = cnt[t];
                                int s = segstart[t];
                                complete = (s / CHUNK) == ((s + c - 1) / CHUNK);
                            }
                            if (complete) {
                                float denom = (float)c + 0.0001f;
                                if (lane < 48) {
                                    float2 wv; wv.x = ax / denom; wv.y = ay / denom;
                                    ((float2*)(out + (size_t)t * C_))[lane] = wv;
                                }
                                if (lane == 0) cnt_out[t] = (float)c;
                            } else if (lane < 48) {
                                unsafeAtomicAdd(out + (size_t)t * C_ + 2 * lane,     ax);
                                unsafeAtomicAdd(out + (size_t)t * C_ + 2 * lane + 1, ay);
                            }
                        }
                        cur = tt[j]; run_start = k; ax = 0.0f; ay = 0.0f;
                    }
                    ax += vbuf[j].x; ay += vbuf[j].y;
                }
            }
            if (cur >= 0) {                       // flush final run [run_start, n)
                int t = cur, ks = run_start;
                int c; bool complete;
                c = cnt[t];
                int s = segstart[t];
                complete = (s / CHUNK) == ((s + c - 1) / CHUNK);
                if (ks > 0 && complete) { /* middle-run shortcut not valid at chunk end */ }
                if (complete) {
                    float denom = (float)c + 0.0001f;
                    if (lane < 48) {
                        float2 wv; wv.x = ax / denom; wv.y = ay / denom;
                        ((float2*)(out + (size_t)t * C_))[lane] = wv;
                    }
                    if (lane == 0) cnt_out[t] = (float)c;
                } else if (lane < 48) {
                    unsafeAtomicAdd(out + (size_t)t * C_ + 2 * lane,     ax);
                    unsafeAtomicAdd(out + (size_t)t * C_ + 2 * lane + 1, ay);
                }
            }
        }
    }
    gbar(ctr, 6 * NB);

    // ============ phase 6: finalize (crossing divide + empty rows) ==========
    for (int vox = wvg; vox < NVOX; vox += NWAVE) {
        int c = cnt[vox];
        if (c == 0) {
            if (lane < 48) {
                float2 z; z.x = 0.0f; z.y = 0.0f;
                ((float2*)(out + (size_t)vox * C_))[lane] = z;
            }
            if (lane == 0) cnt_out[vox] = 0.0f;
            continue;
        }
        int s = segstart[vox], e = s + c;
        if (s / CHUNK == (e - 1) / CHUNK) continue;   // complete: written in phase 5
        float denom = (float)c + 0.0001f;
        if (lane < 48) {
            float2* o = (float2*)(out + (size_t)vox * C_);
            float2 x = o[lane];
            x.x /= denom; x.y /= denom;
            o[lane] = x;
        }
        if (lane == 0) cnt_out[vox] = (float)c;
    }
}

extern "C" void kernel_launch(void* const* d_in, const int* in_sizes, int n_in,
                              void* d_out, int out_size, void* d_ws, size_t ws_size,
                              hipStream_t stream) {
    const float* feats  = (const float*)d_in[0];
    const int*   coords = (const int*)d_in[1];
    const float* vm     = (const float*)d_in[2];
    const float* intr   = (const float*)d_in[3];

    float* out     = (float*)d_out;                  // NVOX*C_ floats
    float* cnt_out = out + (size_t)NVOX * C_;        // NVOX floats

    char* ws = (char*)d_ws;
    // --- zero region (one memset): sneg | cnt | mask | gtotal | ctr ---
    int*                sneg   = (int*)(ws + 0);             // 24 B (pad to 32)
    int*                cnt    = (int*)(ws + 32);            // 800,000 B
    unsigned long long* mask   = (unsigned long long*)(ws + 800032);  // 524,288 B
    int*                gtotal = (int*)(ws + 1324320);       // 4 B
    int*                ctr    = (int*)(ws + 1324324);       // 4 B -> zero region ends 1324328
    // --- uninitialized scratch ---
    int*  tgt       = (int*)(ws + 1324352);                  // 614,400 B
    int*  segstart  = (int*)(ws + 1938752);                  // 800,000 B
    int*  cursor    = (int*)(ws + 2738752);                  // 800,000 B
    int2* sorted_rt = (int2*)(ws + 3538752);                 // 1,228,800 B
    int*  occ       = (int*)(ws + 4767552);                  // 33,554,432 B (mask-gated)

    hipMemsetAsync(ws, 0, 1324352, stream);                  // single fill

    mega_kernel<<<NB, BT, 0, stream>>>(feats, coords, vm, intr,
                                       sneg, cnt, mask, gtotal, ctr,
                                       tgt, segstart, cursor, sorted_rt, occ,
                                       out, cnt_out);
}

// Round 9
// 260.769 us; speedup vs baseline: 3.6474x; 3.6474x over previous
//
#include <hip/hip_runtime.h>
#include <hip/hip_bf16.h>
#include <climits>

#define B_ 2
#define V_ 4
#define H_ 120
#define W_ 160
#define C_ 96
#define NVOX 200000
#define GRID_ 128
#define NSTEPS 156
#define NRAYS (B_*V_*H_*W_)       // 153600
#define NB1 ((NVOX + 255) / 256)  // 782 blocks over voxels
#define CHUNK 32                  // sorted-list entries per wave in chunk_reduce
#define NCHUNK ((NRAYS + CHUNK - 1) / CHUNK)  // 4800 max chunks
#define PARR 4                    // lanes cooperating per ray in march

// ---- Kernel A: per-batch min via atomicMax(127-coord) (sneg zero-init) -----
__global__ void shift_kernel(const int* __restrict__ coords, int* __restrict__ sneg) {
    __shared__ int smax[B_ * 3];
    int t = threadIdx.x;
    if (t < B_ * 3) smax[t] = 0;
    __syncthreads();
    int i = blockIdx.x * blockDim.x + t;
    if (i < NVOX) {
        int b = coords[i * 4 + 0];
        atomicMax(&smax[b * 3 + 0], 127 - coords[i * 4 + 1]);
        atomicMax(&smax[b * 3 + 1], 127 - coords[i * 4 + 2]);
        atomicMax(&smax[b * 3 + 2], 127 - coords[i * 4 + 3]);
    }
    __syncthreads();
    if (t < B_ * 3 && smax[t] > 0) atomicMax(&sneg[t], smax[t]);
}

// ------- Kernel B: occ id grid (last-dup wins) + 64-bit occupancy bitmask ---
// occ is NOT pre-initialized (poison is negative, mask gates all reads).
__global__ void occ_kernel(const int* __restrict__ coords,
                           const int* __restrict__ sneg,
                           int* __restrict__ occ,
                           unsigned long long* __restrict__ mask) {
    int i = blockIdx.x * blockDim.x + threadIdx.x;
    if (i >= NVOX) return;
    int b = coords[i * 4 + 0];
    int x = coords[i * 4 + 1] - (127 - sneg[b * 3 + 0]);
    int y = coords[i * 4 + 2] - (127 - sneg[b * 3 + 1]);
    int z = coords[i * 4 + 3] - (127 - sneg[b * 3 + 2]);
    int idx = ((b * GRID_ + z) * GRID_ + y) * GRID_ + x;
    atomicMax(&occ[idx], i);
    atomicOr(&mask[idx >> 6], 1ull << (idx & 63));
}

// -------- Kernel C: step-parallel march, d-vector FMA form ------------------
// Wave = 16 consecutive pixels x 4 step-blocks of 8 steps. Per step: 3 FMA
// (pw = d*t + tr with d = R*(dx,dy,1)) + floor/clamp. 64-bit mask words with
// per-lane dedup of repeated word indices.
__global__ void march_kernel(const float* __restrict__ vm,
                             const float* __restrict__ intr,
                             const int* __restrict__ sneg,
                             const unsigned long long* __restrict__ mask,
                             const int* __restrict__ occ,
                             int* __restrict__ tgt,
                             int* __restrict__ cnt) {
    int gt   = blockIdx.x * blockDim.x + threadIdx.x;
    int lane = threadIdx.x & 63;
    int p    = lane & 15;
    int sub  = lane >> 4;
    int r    = ((gt >> 6) << 4) + p;
    if (r >= NRAYS) return;
    int w = r % W_;
    int h = (r / W_) % H_;
    int v = (r / (W_ * H_)) % V_;
    int b = r / (W_ * H_ * V_);
    const float* M = vm + (size_t)(b * V_ + v) * 16;
    float fx = intr[0], fy = intr[1], cx = intr[2], cy = intr[3];
    float dx = ((float)w + 0.5f - cx) / fx;
    float dy = ((float)h + 0.5f - cy) / fy;
    // d = R * (dx, dy, 1)
    float d0 = M[0] * dx + M[1] * dy + M[2];
    float d1 = M[4] * dx + M[5] * dy + M[6];
    float d2 = M[8] * dx + M[9] * dy + M[10];
    float t0 = M[3]  - (float)(127 - sneg[b * 3 + 0]);
    float t1 = M[7]  - (float)(127 - sneg[b * 3 + 1]);
    float t2 = M[11] - (float)(127 - sneg[b * 3 + 2]);
    const int vbase = b * GRID_ * GRID_ * GRID_;
    const int MISS = 0x7FFFFFFF;
    int beststep = MISS;
    for (int w0 = 0; w0 < NSTEPS; w0 += 32) {
        int lin[8]; bool ok[8];
#pragma unroll
        for (int j = 0; j < 8; ++j) {
            int st = w0 + sub * 8 + j;
            float t = 2.0f + 0.5f * (float)st;
            float pwx = d0 * t + t0;
            float pwy = d1 * t + t1;
            float pwz = d2 * t + t2;
            int ix = (int)floorf(pwx);
            int iy = (int)floorf(pwy);
            int iz = (int)floorf(pwz);
            ok[j] = ((unsigned)ix < (unsigned)GRID_) &
                    ((unsigned)iy < (unsigned)GRID_) &
                    ((unsigned)iz < (unsigned)GRID_) & (st < NSTEPS);
            int cix = min(max(ix, 0), GRID_ - 1);
            int ciy = min(max(iy, 0), GRID_ - 1);
            int ciz = min(max(iz, 0), GRID_ - 1);
            lin[j] = vbase + (ciz << 14) + (ciy << 7) + cix;
        }
        unsigned long long u[8];
        bool same[8];
        same[0] = false;
#pragma unroll
        for (int j = 1; j < 8; ++j) same[j] = ((lin[j] >> 6) == (lin[j - 1] >> 6));
#pragma unroll
        for (int j = 0; j < 8; ++j)
            if (!same[j]) u[j] = mask[lin[j] >> 6];
#pragma unroll
        for (int j = 1; j < 8; ++j)
            if (same[j]) u[j] = u[j - 1];
        int local = MISS;
#pragma unroll
        for (int j = 0; j < 8; ++j) {
            int st = w0 + sub * 8 + j;
            if (ok[j] && ((u[j] >> (lin[j] & 63)) & 1ull)) local = min(local, st);
        }
        local = min(local, __shfl_xor(local, 16));
        local = min(local, __shfl_xor(local, 32));
        if (local != MISS) { beststep = local; break; }
    }
    if (sub == 0) {
        int res = -1;
        if (beststep != MISS) {
            float t = 2.0f + 0.5f * (float)beststep;
            int ix = (int)floorf(d0 * t + t0);
            int iy = (int)floorf(d1 * t + t1);
            int iz = (int)floorf(d2 * t + t2);
            res = occ[vbase + (iz << 14) + (iy << 7) + ix];
        }
        tgt[r] = res;
        if (res >= 0) atomicAdd(&cnt[res], 1);
    }
}

// ---- Kernel D: segment allocator + crossing worklist -----------------------
__global__ void alloc_kernel(const int* __restrict__ cnt,
                             int* __restrict__ gtotal,
                             int* __restrict__ segstart,
                             int* __restrict__ cursor,
                             int* __restrict__ wl,
                             int* __restrict__ wlcount) {
    __shared__ int wtot[4];
    int tid  = threadIdx.x;
    int lane = tid & 63;
    int wid  = tid >> 6;
    int i = blockIdx.x * 256 + tid;
    int c = (i < NVOX) ? cnt[i] : 0;
    int x = c;
#pragma unroll
    for (int d = 1; d < 64; d <<= 1) {
        int y = __shfl_up(x, d);
        if (lane >= d) x += y;
    }
    if (lane == 63) wtot[wid] = x;
    __syncthreads();
    if (tid == 0) {
        int s0 = wtot[0], s1 = wtot[1], s2 = wtot[2], s3 = wtot[3];
        int base = atomicAdd(gtotal, s0 + s1 + s2 + s3);
        wtot[0] = base;
        wtot[1] = base + s0;
        wtot[2] = base + s0 + s1;
        wtot[3] = base + s0 + s1 + s2;
    }
    __syncthreads();
    if (i >= NVOX) return;
    int s = wtot[wid] + (x - c);
    segstart[i] = s;
    cursor[i]   = s;
    if (c > 0 && (s / CHUNK) != ((s + c - 1) / CHUNK)) {
        int pidx = atomicAdd(wlcount, 1);
        wl[pidx] = i;                 // crossing voxel -> finalize worklist
    }
}

// ---- Kernel E: wave-aggregated bucket scatter ------------------------------
// Consecutive rays cluster by target: detect runs in-wave, one atomic per run.
__global__ void order_kernel(const int* __restrict__ tgt,
                             int* __restrict__ cursor, int2* __restrict__ sorted_rt) {
    int r = blockIdx.x * blockDim.x + threadIdx.x;   // grid is exactly NRAYS
    int lane = threadIdx.x & 63;
    int t = tgt[r];
    bool active = t >= 0;
    int prev = __shfl_up(t, 1);
    bool head = active && (lane == 0 || prev != t);
    bool boundary = head || !active;
    unsigned long long bb = __ballot(boundary);
    unsigned long long below = bb & ((2ull << lane) - 1);   // bits 0..lane
    int headpos = 63 - __clzll(below | 1ull);               // nearest boundary <= lane
    int base = 0;
    if (head) {
        unsigned long long above = bb & ~((2ull << lane) - 1);  // bits > lane
        int next = above ? (__ffsll((long long)above) - 1) : 64;
        int runlen = next - lane;
        base = atomicAdd(&cursor[t], runlen);
    }
    base = __shfl(base, headpos);
    if (active) sorted_rt[base + (lane - headpos)] = make_int2(r, t);
}

// ---------------- run flush: middle runs need no cnt/segstart ---------------
__device__ __forceinline__ void flush_run2(int t, int ks, int ke, int n,
                                           float ax, float ay, int lane,
                                           const int* __restrict__ segstart,
                                           const int* __restrict__ cnt,
                                           float* __restrict__ out,
                                           float* __restrict__ cnt_out) {
    int c;
    bool complete;
    if (ks > 0 && ke < n) {          // middle run: whole segment inside chunk
        c = ke - ks;
        complete = true;
    } else {
        c = cnt[t];
        int s = segstart[t];
        complete = (s / CHUNK) == ((s + c - 1) / CHUNK);
    }
    if (complete) {
        float denom = (float)c + 0.0001f;
        if (lane < 48) {
            float2 wv; wv.x = ax / denom; wv.y = ay / denom;
            ((float2*)(out + (size_t)t * C_))[lane] = wv;
        }
        if (lane == 0) cnt_out[t] = (float)c;
    } else if (lane < 48) {          // crossing: accumulate into memset-zeroed row
        unsafeAtomicAdd(out + (size_t)t * C_ + 2 * lane,     ax);
        unsafeAtomicAdd(out + (size_t)t * C_ + 2 * lane + 1, ay);
    }
}

// ---------------- Kernel F: chunked segmented reduce (8-deep pipeline) ------
__global__ void chunk_reduce_kernel(const float* __restrict__ feats,
                                    const int2* __restrict__ sorted_rt,
                                    const int* __restrict__ segstart,
                                    const int* __restrict__ cnt,
                                    const int* __restrict__ total_p,
                                    float* __restrict__ out,
                                    float* __restrict__ cnt_out) {
    int wave = (blockIdx.x * blockDim.x + threadIdx.x) >> 6;
    int lane = threadIdx.x & 63;
    int total = total_p[0];
    int a = wave * CHUNK;
    if (a >= total) return;
    int n = min(CHUNK, total - a);
    int myr = 0, myt = 0;
    if (lane < n) { int2 e = sorted_rt[a + lane]; myr = e.x; myt = e.y; }
    float ax = 0.0f, ay = 0.0f;
    int cur = -1, run_start = 0;
    for (int k0 = 0; k0 < n; k0 += 8) {
        float2 vbuf[8]; int tt[8];
#pragma unroll
        for (int j = 0; j < 8; ++j) {             // issue 8 feature loads
            int k = k0 + j;
            int rr = __shfl(myr, k);
            tt[j]  = __shfl(myt, k);
            vbuf[j] = make_float2(0.0f, 0.0f);
            if (k < n && lane < 48)
                vbuf[j] = ((const float2*)(feats + (size_t)rr * C_))[lane];
        }
#pragma unroll
        for (int j = 0; j < 8; ++j) {
            int k = k0 + j;
            if (k >= n) break;
            if (tt[j] != cur) {
                if (cur >= 0)
                    flush_run2(cur, run_start, k, n, ax, ay, lane, segstart, cnt, out, cnt_out);
                cur = tt[j]; run_start = k; ax = 0.0f; ay = 0.0f;
            }
            ax += vbuf[j].x; ay += vbuf[j].y;
        }
    }
    flush_run2(cur, run_start, n, n, ax, ay, lane, segstart, cnt, out, cnt_out);
}

// ---- Kernel G: finalize crossing voxels from worklist ----------------------
// Empty rows + empty cnt_out covered by the d_out memset.
__global__ void finalize_kernel(const int* __restrict__ wl,
                                const int* __restrict__ wlcount,
                                const int* __restrict__ cnt,
                                float* __restrict__ out,
                                float* __restrict__ cnt_out) {
    int idx  = (blockIdx.x * blockDim.x + threadIdx.x) >> 6;
    int lane = threadIdx.x & 63;
    if (idx >= wlcount[0]) return;
    int vox = wl[idx];
    int c = cnt[vox];
    float denom = (float)c + 0.0001f;
    if (lane < 48) {
        float2* o = (float2*)(out + (size_t)vox * C_);
        float2 x = o[lane];
        x.x /= denom; x.y /= denom;
        o[lane] = x;
    }
    if (lane == 0) cnt_out[vox] = (float)c;
}

extern "C" void kernel_launch(void* const* d_in, const int* in_sizes, int n_in,
                              void* d_out, int out_size, void* d_ws, size_t ws_size,
                              hipStream_t stream) {
    const float* feats  = (const float*)d_in[0];
    const int*   coords = (const int*)d_in[1];
    const float* vm     = (const float*)d_in[2];
    const float* intr   = (const float*)d_in[3];

    float* out     = (float*)d_out;                  // NVOX*C_ floats
    float* cnt_out = out + (size_t)NVOX * C_;        // NVOX floats

    char* ws = (char*)d_ws;
    // --- zero region (one memset): sneg | cnt | mask | gtotal | wlcount ---
    int*                sneg    = (int*)(ws + 0);            // 24 B (pad to 64)
    int*                cnt     = (int*)(ws + 64);           // 800,000 B
    unsigned long long* mask    = (unsigned long long*)(ws + 800064); // 524,288 B
    int*                gtotal  = (int*)(ws + 1324352);      // 4 B
    int*                wlcount = (int*)(ws + 1324356);      // 4 B -> zero ends 1324360
    // --- uninitialized scratch ---
    int*  tgt       = (int*)(ws + 1324416);                  // 614,400 B
    int*  segstart  = (int*)(ws + 1938816);                  // 800,000 B
    int*  cursor    = (int*)(ws + 2738816);                  // 800,000 B
    int*  wl        = (int*)(ws + 3538816);                  // 19,200 B
    int2* sorted_rt = (int2*)(ws + 3558016);                 // 1,228,800 B
    int*  occ       = (int*)(ws + 4786816);                  // 33,554,432 B (mask-gated)

    hipMemsetAsync(ws, 0, 1324360, stream);                  // small zero region
    hipMemsetAsync(d_out, 0, (size_t)out_size * sizeof(float), stream); // 77 MB linear

    shift_kernel<<<NB1, 256, 0, stream>>>(coords, sneg);
    occ_kernel<<<NB1, 256, 0, stream>>>(coords, sneg, occ, mask);
    march_kernel<<<(NRAYS * PARR + 255) / 256, 256, 0, stream>>>(vm, intr, sneg, mask, occ, tgt, cnt);
    alloc_kernel<<<NB1, 256, 0, stream>>>(cnt, gtotal, segstart, cursor, wl, wlcount);
    order_kernel<<<NRAYS / 256, 256, 0, stream>>>(tgt, cursor, sorted_rt);
    chunk_reduce_kernel<<<(NCHUNK * 64 + 255) / 256, 256, 0, stream>>>(
        feats, sorted_rt, segstart, cnt, gtotal, out, cnt_out);
    finalize_kernel<<<(NCHUNK * 64 + 255) / 256, 256, 0, stream>>>(
        wl, wlcount, cnt, out, cnt_out);
}

// Round 10
// 237.231 us; speedup vs baseline: 4.0093x; 1.0992x over previous
//
#include <hip/hip_runtime.h>
#include <hip/hip_bf16.h>
#include <climits>

#define B_ 2
#define V_ 4
#define H_ 120
#define W_ 160
#define C_ 96
#define NVOX 200000
#define GRID_ 128
#define NSTEPS 156
#define NRAYS (B_*V_*H_*W_)       // 153600
#define NB1 ((NVOX + 255) / 256)  // 782 blocks over voxels
#define CHUNK 32                  // sorted-list entries per wave in chunk_reduce
#define NCHUNK ((NRAYS + CHUNK - 1) / CHUNK)  // 4800 max chunks
#define PARR 4                    // lanes cooperating per ray in march

// ---- Kernel A: per-batch min via atomicMax(127-coord) (sneg zero-init) -----
__global__ void shift_kernel(const int* __restrict__ coords, int* __restrict__ sneg) {
    __shared__ int smax[B_ * 3];
    int t = threadIdx.x;
    if (t < B_ * 3) smax[t] = 0;
    __syncthreads();
    int i = blockIdx.x * blockDim.x + t;
    if (i < NVOX) {
        int b = coords[i * 4 + 0];
        atomicMax(&smax[b * 3 + 0], 127 - coords[i * 4 + 1]);
        atomicMax(&smax[b * 3 + 1], 127 - coords[i * 4 + 2]);
        atomicMax(&smax[b * 3 + 2], 127 - coords[i * 4 + 3]);
    }
    __syncthreads();
    if (t < B_ * 3 && smax[t] > 0) atomicMax(&sneg[t], smax[t]);
}

// ------- Kernel B: occ id grid (last-dup wins) + 64-bit occupancy bitmask ---
// occ is NOT pre-initialized (poison irrelevant: mask gates all reads).
__global__ void occ_kernel(const int* __restrict__ coords,
                           const int* __restrict__ sneg,
                           int* __restrict__ occ,
                           unsigned long long* __restrict__ mask) {
    int i = blockIdx.x * blockDim.x + threadIdx.x;
    if (i >= NVOX) return;
    int b = coords[i * 4 + 0];
    int x = coords[i * 4 + 1] - (127 - sneg[b * 3 + 0]);
    int y = coords[i * 4 + 2] - (127 - sneg[b * 3 + 1]);
    int z = coords[i * 4 + 3] - (127 - sneg[b * 3 + 2]);
    int idx = ((b * GRID_ + z) * GRID_ + y) * GRID_ + x;
    atomicMax(&occ[idx], i);
    atomicOr(&mask[idx >> 6], 1ull << (idx & 63));
}

// -------- Kernel C: step-parallel march + WAVE-AGGREGATED cnt update --------
// Wave = 16 consecutive pixels x 4 step-blocks of 8 steps. The cnt histogram
// update detects contiguous equal-target runs across the 16 result lanes and
// issues ONE atomicAdd(cnt, runlen) per run — near-depth hot voxels receive
// ~16x fewer serialized same-address RMWs.
__global__ void march_kernel(const float* __restrict__ vm,
                             const float* __restrict__ intr,
                             const int* __restrict__ sneg,
                             const unsigned long long* __restrict__ mask,
                             const int* __restrict__ occ,
                             int* __restrict__ tgt,
                             int* __restrict__ cnt) {
    int gt   = blockIdx.x * blockDim.x + threadIdx.x;
    int lane = threadIdx.x & 63;
    int p    = lane & 15;
    int sub  = lane >> 4;
    int r    = ((gt >> 6) << 4) + p;
    if (r >= NRAYS) return;
    int w = r % W_;
    int h = (r / W_) % H_;
    int v = (r / (W_ * H_)) % V_;
    int b = r / (W_ * H_ * V_);
    const float* M = vm + (size_t)(b * V_ + v) * 16;
    float fx = intr[0], fy = intr[1], cx = intr[2], cy = intr[3];
    float dx = ((float)w + 0.5f - cx) / fx;
    float dy = ((float)h + 0.5f - cy) / fy;
    // d = R * (dx, dy, 1)
    float d0 = M[0] * dx + M[1] * dy + M[2];
    float d1 = M[4] * dx + M[5] * dy + M[6];
    float d2 = M[8] * dx + M[9] * dy + M[10];
    float t0 = M[3]  - (float)(127 - sneg[b * 3 + 0]);
    float t1 = M[7]  - (float)(127 - sneg[b * 3 + 1]);
    float t2 = M[11] - (float)(127 - sneg[b * 3 + 2]);
    const int vbase = b * GRID_ * GRID_ * GRID_;
    const int MISS = 0x7FFFFFFF;
    int beststep = MISS;
    for (int w0 = 0; w0 < NSTEPS; w0 += 32) {
        int lin[8]; bool ok[8];
#pragma unroll
        for (int j = 0; j < 8; ++j) {
            int st = w0 + sub * 8 + j;
            float t = 2.0f + 0.5f * (float)st;
            float pwx = d0 * t + t0;
            float pwy = d1 * t + t1;
            float pwz = d2 * t + t2;
            int ix = (int)floorf(pwx);
            int iy = (int)floorf(pwy);
            int iz = (int)floorf(pwz);
            ok[j] = ((unsigned)ix < (unsigned)GRID_) &
                    ((unsigned)iy < (unsigned)GRID_) &
                    ((unsigned)iz < (unsigned)GRID_) & (st < NSTEPS);
            int cix = min(max(ix, 0), GRID_ - 1);
            int ciy = min(max(iy, 0), GRID_ - 1);
            int ciz = min(max(iz, 0), GRID_ - 1);
            lin[j] = vbase + (ciz << 14) + (ciy << 7) + cix;
        }
        unsigned long long u[8];
        bool same[8];
        same[0] = false;
#pragma unroll
        for (int j = 1; j < 8; ++j) same[j] = ((lin[j] >> 6) == (lin[j - 1] >> 6));
#pragma unroll
        for (int j = 0; j < 8; ++j)
            if (!same[j]) u[j] = mask[lin[j] >> 6];
#pragma unroll
        for (int j = 1; j < 8; ++j)
            if (same[j]) u[j] = u[j - 1];
        int local = MISS;
#pragma unroll
        for (int j = 0; j < 8; ++j) {
            int st = w0 + sub * 8 + j;
            if (ok[j] && ((u[j] >> (lin[j] & 63)) & 1ull)) local = min(local, st);
        }
        local = min(local, __shfl_xor(local, 16));
        local = min(local, __shfl_xor(local, 32));
        if (local != MISS) { beststep = local; break; }
    }
    // resolve first-hit id (only the 16 result lanes read occ)
    int res = -1;
    if (sub == 0) {
        if (beststep != MISS) {
            float t = 2.0f + 0.5f * (float)beststep;
            int ix = (int)floorf(d0 * t + t0);
            int iy = (int)floorf(d1 * t + t1);
            int iz = (int)floorf(d2 * t + t2);
            res = occ[vbase + (iz << 14) + (iy << 7) + ix];
        }
        tgt[r] = res;
    }
    // wave-aggregated histogram: one atomic per contiguous equal-target run
    bool active = (sub == 0) && (res >= 0);
    int prevres = __shfl_up(res, 1);
    bool head = active && (p == 0 || prevres != res);
    bool boundary = head || !active;
    unsigned long long bb = __ballot(boundary);
    if (head) {
        unsigned long long above = bb & ~((2ull << lane) - 1);  // boundaries > lane
        int next = above ? (__ffsll((long long)above) - 1) : 64;
        atomicAdd(&cnt[res], next - lane);                      // run length
    }
}

// ---- Kernel D: segment allocator + crossing worklist -----------------------
__global__ void alloc_kernel(const int* __restrict__ cnt,
                             int* __restrict__ gtotal,
                             int* __restrict__ segstart,
                             int* __restrict__ cursor,
                             int* __restrict__ wl,
                             int* __restrict__ wlcount) {
    __shared__ int wtot[4];
    int tid  = threadIdx.x;
    int lane = tid & 63;
    int wid  = tid >> 6;
    int i = blockIdx.x * 256 + tid;
    int c = (i < NVOX) ? cnt[i] : 0;
    int x = c;
#pragma unroll
    for (int d = 1; d < 64; d <<= 1) {
        int y = __shfl_up(x, d);
        if (lane >= d) x += y;
    }
    if (lane == 63) wtot[wid] = x;
    __syncthreads();
    if (tid == 0) {
        int s0 = wtot[0], s1 = wtot[1], s2 = wtot[2], s3 = wtot[3];
        int base = atomicAdd(gtotal, s0 + s1 + s2 + s3);
        wtot[0] = base;
        wtot[1] = base + s0;
        wtot[2] = base + s0 + s1;
        wtot[3] = base + s0 + s1 + s2;
    }
    __syncthreads();
    if (i >= NVOX) return;
    int s = wtot[wid] + (x - c);
    segstart[i] = s;
    cursor[i]   = s;
    if (c > 0 && (s / CHUNK) != ((s + c - 1) / CHUNK)) {
        int pidx = atomicAdd(wlcount, 1);
        wl[pidx] = i;                 // crossing voxel -> finalize worklist
    }
}

// ---- Kernel E: wave-aggregated bucket scatter ------------------------------
__global__ void order_kernel(const int* __restrict__ tgt,
                             int* __restrict__ cursor, int2* __restrict__ sorted_rt) {
    int r = blockIdx.x * blockDim.x + threadIdx.x;   // grid is exactly NRAYS
    int lane = threadIdx.x & 63;
    int t = tgt[r];
    bool active = t >= 0;
    int prev = __shfl_up(t, 1);
    bool head = active && (lane == 0 || prev != t);
    bool boundary = head || !active;
    unsigned long long bb = __ballot(boundary);
    unsigned long long below = bb & ((2ull << lane) - 1);   // bits 0..lane
    int headpos = 63 - __clzll(below | 1ull);               // nearest boundary <= lane
    int base = 0;
    if (head) {
        unsigned long long above = bb & ~((2ull << lane) - 1);  // bits > lane
        int next = above ? (__ffsll((long long)above) - 1) : 64;
        int runlen = next - lane;
        base = atomicAdd(&cursor[t], runlen);
    }
    base = __shfl(base, headpos);
    if (active) sorted_rt[base + (lane - headpos)] = make_int2(r, t);
}

// ---------------- run flush: middle runs need no cnt/segstart ---------------
__device__ __forceinline__ void flush_run2(int t, int ks, int ke, int n,
                                           float ax, float ay, int lane,
                                           const int* __restrict__ segstart,
                                           const int* __restrict__ cnt,
                                           float* __restrict__ out,
                                           float* __restrict__ cnt_out) {
    int c;
    bool complete;
    if (ks > 0 && ke < n) {          // middle run: whole segment inside chunk
        c = ke - ks;
        complete = true;
    } else {
        c = cnt[t];
        int s = segstart[t];
        complete = (s / CHUNK) == ((s + c - 1) / CHUNK);
    }
    if (complete) {
        float denom = (float)c + 0.0001f;
        if (lane < 48) {
            float2 wv; wv.x = ax / denom; wv.y = ay / denom;
            ((float2*)(out + (size_t)t * C_))[lane] = wv;
        }
        if (lane == 0) cnt_out[t] = (float)c;
    } else if (lane < 48) {          // crossing: accumulate into memset-zeroed row
        unsafeAtomicAdd(out + (size_t)t * C_ + 2 * lane,     ax);
        unsafeAtomicAdd(out + (size_t)t * C_ + 2 * lane + 1, ay);
    }
}

// ---------------- Kernel F: chunked segmented reduce (8-deep pipeline) ------
__global__ void chunk_reduce_kernel(const float* __restrict__ feats,
                                    const int2* __restrict__ sorted_rt,
                                    const int* __restrict__ segstart,
                                    const int* __restrict__ cnt,
                                    const int* __restrict__ total_p,
                                    float* __restrict__ out,
                                    float* __restrict__ cnt_out) {
    int wave = (blockIdx.x * blockDim.x + threadIdx.x) >> 6;
    int lane = threadIdx.x & 63;
    int total = total_p[0];
    int a = wave * CHUNK;
    if (a >= total) return;
    int n = min(CHUNK, total - a);
    int myr = 0, myt = 0;
    if (lane < n) { int2 e = sorted_rt[a + lane]; myr = e.x; myt = e.y; }
    float ax = 0.0f, ay = 0.0f;
    int cur = -1, run_start = 0;
    for (int k0 = 0; k0 < n; k0 += 8) {
        float2 vbuf[8]; int tt[8];
#pragma unroll
        for (int j = 0; j < 8; ++j) {             // issue 8 feature loads
            int k = k0 + j;
            int rr = __shfl(myr, k);
            tt[j]  = __shfl(myt, k);
            vbuf[j] = make_float2(0.0f, 0.0f);
            if (k < n && lane < 48)
                vbuf[j] = ((const float2*)(feats + (size_t)rr * C_))[lane];
        }
#pragma unroll
        for (int j = 0; j < 8; ++j) {
            int k = k0 + j;
            if (k >= n) break;
            if (tt[j] != cur) {
                if (cur >= 0)
                    flush_run2(cur, run_start, k, n, ax, ay, lane, segstart, cnt, out, cnt_out);
                cur = tt[j]; run_start = k; ax = 0.0f; ay = 0.0f;
            }
            ax += vbuf[j].x; ay += vbuf[j].y;
        }
    }
    flush_run2(cur, run_start, n, n, ax, ay, lane, segstart, cnt, out, cnt_out);
}

// ---- Kernel G: finalize crossing voxels from worklist ----------------------
// Empty rows + empty cnt_out covered by the d_out memset.
__global__ void finalize_kernel(const int* __restrict__ wl,
                                const int* __restrict__ wlcount,
                                const int* __restrict__ cnt,
                                float* __restrict__ out,
                                float* __restrict__ cnt_out) {
    int idx  = (blockIdx.x * blockDim.x + threadIdx.x) >> 6;
    int lane = threadIdx.x & 63;
    if (idx >= wlcount[0]) return;
    int vox = wl[idx];
    int c = cnt[vox];
    float denom = (float)c + 0.0001f;
    if (lane < 48) {
        float2* o = (float2*)(out + (size_t)vox * C_);
        float2 x = o[lane];
        x.x /= denom; x.y /= denom;
        o[lane] = x;
    }
    if (lane == 0) cnt_out[vox] = (float)c;
}

extern "C" void kernel_launch(void* const* d_in, const int* in_sizes, int n_in,
                              void* d_out, int out_size, void* d_ws, size_t ws_size,
                              hipStream_t stream) {
    const float* feats  = (const float*)d_in[0];
    const int*   coords = (const int*)d_in[1];
    const float* vm     = (const float*)d_in[2];
    const float* intr   = (const float*)d_in[3];

    float* out     = (float*)d_out;                  // NVOX*C_ floats
    float* cnt_out = out + (size_t)NVOX * C_;        // NVOX floats

    char* ws = (char*)d_ws;
    // --- zero region (one memset): sneg | cnt | mask | gtotal | wlcount ---
    int*                sneg    = (int*)(ws + 0);            // 24 B (pad to 64)
    int*                cnt     = (int*)(ws + 64);           // 800,000 B
    unsigned long long* mask    = (unsigned long long*)(ws + 800064); // 524,288 B
    int*                gtotal  = (int*)(ws + 1324352);      // 4 B
    int*                wlcount = (int*)(ws + 1324356);      // 4 B -> zero ends 1324360
    // --- uninitialized scratch ---
    int*  tgt       = (int*)(ws + 1324416);                  // 614,400 B
    int*  segstart  = (int*)(ws + 1938816);                  // 800,000 B
    int*  cursor    = (int*)(ws + 2738816);                  // 800,000 B
    int*  wl        = (int*)(ws + 3538816);                  // 19,200 B
    int2* sorted_rt = (int2*)(ws + 3558016);                 // 1,228,800 B
    int*  occ       = (int*)(ws + 4786816);                  // 33,554,432 B (mask-gated)

    hipMemsetAsync(ws, 0, 1324360, stream);                  // small zero region
    hipMemsetAsync(d_out, 0, (size_t)out_size * sizeof(float), stream); // 77 MB linear

    shift_kernel<<<NB1, 256, 0, stream>>>(coords, sneg);
    occ_kernel<<<NB1, 256, 0, stream>>>(coords, sneg, occ, mask);
    march_kernel<<<(NRAYS * PARR + 255) / 256, 256, 0, stream>>>(vm, intr, sneg, mask, occ, tgt, cnt);
    alloc_kernel<<<NB1, 256, 0, stream>>>(cnt, gtotal, segstart, cursor, wl, wlcount);
    order_kernel<<<NRAYS / 256, 256, 0, stream>>>(tgt, cursor, sorted_rt);
    chunk_reduce_kernel<<<(NCHUNK * 64 + 255) / 256, 256, 0, stream>>>(
        feats, sorted_rt, segstart, cnt, gtotal, out, cnt_out);
    finalize_kernel<<<(NCHUNK * 64 + 255) / 256, 256, 0, stream>>>(
        wl, wlcount, cnt, out, cnt_out);
}